// Round 1
// 528.122 us; speedup vs baseline: 1.2665x; 1.2665x over previous
//
#include <hip/hip_runtime.h>
#include <hip/hip_bf16.h>
#include <stdint.h>

#define D_IN    4096
#define D_OUT   4096
#define M_TOT   8192          // B*S = 4*2048
#define R_LORA  16
#define SCALING 2.0f          // lora_alpha / r

typedef __bf16 bf16x8 __attribute__((ext_vector_type(8)));
typedef float  f32x4  __attribute__((ext_vector_type(4)));
typedef short  s16x8  __attribute__((ext_vector_type(8)));

__device__ __forceinline__ void async_ld16(const void* g, void* l) {
    __builtin_amdgcn_global_load_lds(
        (const __attribute__((address_space(1))) void*)g,
        (__attribute__((address_space(3))) void*)l,
        16, 0, 0);
}

// raw barrier (no vmcnt drain) + compiler memory fence on both sides
#define BAR() do { asm volatile("" ::: "memory"); \
                   __builtin_amdgcn_s_barrier(); \
                   asm volatile("" ::: "memory"); } while (0)
#define WAIT_VM(n) asm volatile("s_waitcnt vmcnt(" #n ")" ::: "memory")

// ---------------------------------------------------------------------------
// Kernel 1: W_t[o][i] = (q[i,o]-z[g,o])*s[g,o] + 2.0 * sum_r A[r,i]*B[o,r]
// LoRA B held in registers (old Bbuf[oo][r] LDS layout was a 32-way conflict).
// ---------------------------------------------------------------------------
__global__ __launch_bounds__(256) void build_wt(
    const int*   __restrict__ qweight,   // [D_IN][D_OUT]
    const int*   __restrict__ qzeros,    // [D_IN/128][D_OUT]
    const float* __restrict__ scales,    // [D_IN/128][D_OUT]
    const float* __restrict__ loraA,     // [R][D_IN]
    const float* __restrict__ loraB,     // [D_OUT][R]
    __hip_bfloat16* __restrict__ wt)     // [D_OUT][D_IN]
{
    __shared__ float tile[64][65];       // +1 pad: conflict-free transposed read
    __shared__ float Abuf[16][64];       // loraA[r][i_off] (wave-uniform reads)

    const int i0 = blockIdx.x * 64;
    const int o0 = blockIdx.y * 64;
    const int t  = threadIdx.x;

    for (int j = t; j < 16 * 64; j += 256) {
        int r = j >> 6, io = j & 63;
        Abuf[r][io] = loraA[r * D_IN + i0 + io];
    }
    const int oo = t & 63;
    // loraB row for this thread's o: 16 floats, kept in registers
    const float* bp = loraB + (size_t)(o0 + oo) * R_LORA;
    f32x4 bA = *(const f32x4*)(bp + 0);
    f32x4 bB = *(const f32x4*)(bp + 4);
    f32x4 bC = *(const f32x4*)(bp + 8);
    f32x4 bD = *(const f32x4*)(bp + 12);
    __syncthreads();

    const int g  = i0 >> 7;              // 64-aligned tile never crosses a group
    const int   zero = qzeros[g * D_OUT + o0 + oo];
    const float sc   = scales[g * D_OUT + o0 + oo];

    for (int ii = (t >> 6); ii < 64; ii += 4) {
        int q = qweight[(size_t)(i0 + ii) * D_OUT + o0 + oo];
        float w = (float)(q - zero) * sc;
        float acc = 0.f;
        #pragma unroll
        for (int r = 0; r < 4; ++r)
            acc += Abuf[r][ii]      * bA[r] + Abuf[r + 4][ii]  * bB[r]
                 + Abuf[r + 8][ii]  * bC[r] + Abuf[r + 12][ii] * bD[r];
        tile[ii][oo] = w + SCALING * acc;
    }
    __syncthreads();

    const int i_off  = (t & 31) * 2;
    const int o_base = t >> 5;
    #pragma unroll
    for (int p = 0; p < 8; ++p) {
        int o = o_base + p * 8;
        __hip_bfloat162 v;
        v.x = __float2bfloat16(tile[i_off][o]);
        v.y = __float2bfloat16(tile[i_off + 1][o]);
        *(__hip_bfloat162*)&wt[(size_t)(o0 + o) * D_IN + i0 + i_off] = v;
    }
}

// ---------------------------------------------------------------------------
// Kernel 2: x fp32 -> bf16 (8 elems/thread, 16B stores)
// ---------------------------------------------------------------------------
__global__ __launch_bounds__(256) void cvt_x(
    const float* __restrict__ x, __hip_bfloat16* __restrict__ xb)
{
    size_t idx = ((size_t)blockIdx.x * 256 + threadIdx.x) * 8;
    f32x4 a = *(const f32x4*)(x + idx);
    f32x4 b = *(const f32x4*)(x + idx + 4);
    union { __hip_bfloat16 h[8]; s16x8 v; } u;
    u.h[0] = __float2bfloat16(a[0]); u.h[1] = __float2bfloat16(a[1]);
    u.h[2] = __float2bfloat16(a[2]); u.h[3] = __float2bfloat16(a[3]);
    u.h[4] = __float2bfloat16(b[0]); u.h[5] = __float2bfloat16(b[1]);
    u.h[6] = __float2bfloat16(b[2]); u.h[7] = __float2bfloat16(b[3]);
    *(s16x8*)(xb + idx) = u.v;
}

// ---------------------------------------------------------------------------
// Kernel 3: 256x256x64 8-phase GEMM  C[m][n] = sum_k A[m][k] * Bt[n][k]
//
// LDS (128 KiB dynamic): A tiles [buf0 32K][buf1 32K] then B tiles likewise.
// A tile = 32 subtiles of 1024 B; subtile u = h*16 + i*2 + j holds the
// 16-row x 32-col bf16 block (rows h*128+i*16.., cols j*32..) stored in MFMA
// read order: slot s (=lane) holds global chunk (row s&15, col (s>>4)*8).
//  -> every fragment ds_read_b128 is subtile_base + lane*16: conflict-free.
//  -> global_load_lds dest stays linear; permutation folded into per-lane src.
// 8 waves (2M x 4N), per-wave C = 128x64. 4 phases/K-tile, quadrant order
// (m0-3,n0-1)(m0-3,n2-3)(m4-7,n2-3)(m4-7,n0-1); 16 MFMA each.
// Next tile staged one 16KB quarter per phase into the non-live buffer;
// counted s_waitcnt vmcnt(4) at phases 1,2,4 keeps 2 quarters in flight
// (never drained to 0 in the main loop); last tile drains 4->2->0.
// ---------------------------------------------------------------------------
#define RDA(fm, ks) (*(const bf16x8*)(aRd + ((fm) * 2 + (ks)) * 1024))
#define RDB(fn, ks) (*(const bf16x8*)(bRd + ((fn) * 2 + (ks)) * 1024))

template<bool LAST>
__device__ __forceinline__ void gemm_tile(
    const char* __restrict__ aRd, const char* __restrict__ bRd,
    char* __restrict__ ldsAn, char* __restrict__ ldsBn,
    const __hip_bfloat16* __restrict__ agA,
    const __hip_bfloat16* __restrict__ agB,
    const int w, const int ub, f32x4 (&acc)[8][4])
{
    bf16x8 af[4][2], bf0[2][2], bf1[2][2];

    // ---- phase 1: (m 0-3, n 0-1); stage F1A(next) ----
    #pragma unroll
    for (int fm = 0; fm < 4; ++fm) { af[fm][0] = RDA(fm, 0); af[fm][1] = RDA(fm, 1); }
    #pragma unroll
    for (int fn = 0; fn < 2; ++fn) { bf0[fn][0] = RDB(fn, 0); bf0[fn][1] = RDB(fn, 1); }
    if constexpr (!LAST) {
        async_ld16(agA,                      ldsAn + w * 1024);
        async_ld16(agA + (size_t)128 * D_IN, ldsAn + (16 + w) * 1024);
    }
    BAR();
    __builtin_amdgcn_s_setprio(1);
    #pragma unroll
    for (int fm = 0; fm < 4; ++fm)
        #pragma unroll
        for (int fn = 0; fn < 2; ++fn)
            #pragma unroll
            for (int ks = 0; ks < 2; ++ks)
                acc[fm][fn] = __builtin_amdgcn_mfma_f32_16x16x32_bf16(
                    af[fm][ks], bf0[fn][ks], acc[fm][fn], 0, 0, 0);
    __builtin_amdgcn_s_setprio(0);
    if constexpr (LAST) { WAIT_VM(2); } else { WAIT_VM(4); }
    BAR();

    // ---- phase 2: (m 0-3, n 2-3); stage F1B(next) ----
    #pragma unroll
    for (int fn = 0; fn < 2; ++fn) { bf1[fn][0] = RDB(fn + 2, 0); bf1[fn][1] = RDB(fn + 2, 1); }
    if constexpr (!LAST) {
        async_ld16(agB,                      ldsBn + ub * 1024);
        async_ld16(agB + (size_t)128 * D_IN, ldsBn + (ub + 16) * 1024);
    }
    BAR();
    __builtin_amdgcn_s_setprio(1);
    #pragma unroll
    for (int fm = 0; fm < 4; ++fm)
        #pragma unroll
        for (int fn = 0; fn < 2; ++fn)
            #pragma unroll
            for (int ks = 0; ks < 2; ++ks)
                acc[fm][fn + 2] = __builtin_amdgcn_mfma_f32_16x16x32_bf16(
                    af[fm][ks], bf1[fn][ks], acc[fm][fn + 2], 0, 0, 0);
    __builtin_amdgcn_s_setprio(0);
    if constexpr (LAST) { WAIT_VM(0); } else { WAIT_VM(4); }
    BAR();

    // ---- phase 3: (m 4-7, n 2-3); stage F2B(next); no vmcnt wait ----
    #pragma unroll
    for (int fm = 0; fm < 4; ++fm) { af[fm][0] = RDA(fm + 4, 0); af[fm][1] = RDA(fm + 4, 1); }
    if constexpr (!LAST) {
        async_ld16(agB + (size_t)32 * D_IN,  ldsBn + (ub + 4) * 1024);
        async_ld16(agB + (size_t)160 * D_IN, ldsBn + (ub + 20) * 1024);
    }
    BAR();
    __builtin_amdgcn_s_setprio(1);
    #pragma unroll
    for (int fm = 0; fm < 4; ++fm)
        #pragma unroll
        for (int fn = 0; fn < 2; ++fn)
            #pragma unroll
            for (int ks = 0; ks < 2; ++ks)
                acc[fm + 4][fn + 2] = __builtin_amdgcn_mfma_f32_16x16x32_bf16(
                    af[fm][ks], bf1[fn][ks], acc[fm + 4][fn + 2], 0, 0, 0);
    __builtin_amdgcn_s_setprio(0);
    BAR();

    // ---- phase 4: (m 4-7, n 0-1); stage F3A(next) ----
    if constexpr (!LAST) {
        async_ld16(agA + (size_t)64 * D_IN,  ldsAn + (8 + w) * 1024);
        async_ld16(agA + (size_t)192 * D_IN, ldsAn + (24 + w) * 1024);
    }
    BAR();
    __builtin_amdgcn_s_setprio(1);
    #pragma unroll
    for (int fm = 0; fm < 4; ++fm)
        #pragma unroll
        for (int fn = 0; fn < 2; ++fn)
            #pragma unroll
            for (int ks = 0; ks < 2; ++ks)
                acc[fm + 4][fn] = __builtin_amdgcn_mfma_f32_16x16x32_bf16(
                    af[fm][ks], bf0[fn][ks], acc[fm + 4][fn], 0, 0, 0);
    __builtin_amdgcn_s_setprio(0);
    if constexpr (!LAST) { WAIT_VM(4); }
    BAR();
}

#define BK 64
#define NKT (D_IN / BK)        // 64
#define NWG ((M_TOT / 256) * (D_OUT / 256))   // 32*16 = 512

__global__ __launch_bounds__(512) void gemm_xw(
    const __hip_bfloat16* __restrict__ A,   // [M_TOT][D_IN] bf16
    const __hip_bfloat16* __restrict__ Bt,  // [D_OUT][D_IN] bf16
    float* __restrict__ C)                  // [M_TOT][D_OUT] fp32
{
    extern __shared__ __attribute__((aligned(16))) char lds[];
    char* ldsA = lds;            // [buf0 32K][buf1 32K]
    char* ldsB = lds + 65536;    // [buf0 32K][buf1 32K]

    const int t    = threadIdx.x;
    const int lane = t & 63;
    const int w    = t >> 6;       // 0..7
    const int wgm  = w >> 2;       // 0..1  (row half of C tile)
    const int wgn  = w & 3;        // 0..3  (col quarter)

    // XCD-aware bijective swizzle (NWG % 8 == 0)
    int wg = (int)blockIdx.x;
    wg = (wg & 7) * (NWG / 8) + (wg >> 3);
    const size_t m0 = (size_t)(wg >> 4) * 256;   // D_OUT/256 = 16 col-blocks
    const size_t n0 = (size_t)(wg & 15) * 256;

    const int r  = lane & 15;
    const int qq = lane >> 4;

    // per-thread global staging sources (chunk (r,qq) of this wave's subtiles)
    const size_t arow = m0 + (size_t)(((w >> 1) & 3) * 16 + r);
    const size_t brow = n0 + (size_t)((((w >> 2) & 1) * 4 + ((w >> 1) & 1)) * 16 + r);
    const int    col  = (w & 1) * 32 + qq * 8;
    const __hip_bfloat16* agA = A  + arow * D_IN + col;
    const __hip_bfloat16* agB = Bt + brow * D_IN + col;
    const int ub = (w & 3) + (w >> 2) * 8;       // B staging subtile base

    // per-thread LDS fragment-read bases (lane*16 linear within subtile)
    const char* aRdBase = ldsA + wgm * 16384 + lane * 16;
    const char* bRdBase = ldsB + (wgn >> 1) * 16384 + (wgn & 1) * 8192 + lane * 16;

    f32x4 acc[8][4] = {};

    // prologue: stage all 4 quarters of tile 0 into buf0 (order = wait order)
    async_ld16(agA,                      ldsA + w * 1024);
    async_ld16(agA + (size_t)128 * D_IN, ldsA + (16 + w) * 1024);
    async_ld16(agB,                      ldsB + ub * 1024);
    async_ld16(agB + (size_t)128 * D_IN, ldsB + (ub + 16) * 1024);
    async_ld16(agB + (size_t)32 * D_IN,  ldsB + (ub + 4) * 1024);
    async_ld16(agB + (size_t)160 * D_IN, ldsB + (ub + 20) * 1024);
    async_ld16(agA + (size_t)64 * D_IN,  ldsA + (8 + w) * 1024);
    async_ld16(agA + (size_t)192 * D_IN, ldsA + (24 + w) * 1024);
    WAIT_VM(4);   // F1A,F1B landed; F2B,F3A still in flight
    BAR();

    int p = 0;
    for (int kt = 0; kt < NKT - 1; ++kt) {
        const int kn = (kt + 1) * BK;
        gemm_tile<false>(aRdBase + p * 32768, bRdBase + p * 32768,
                         ldsA + (p ^ 1) * 32768, ldsB + (p ^ 1) * 32768,
                         agA + kn, agB + kn, w, ub, acc);
        p ^= 1;
    }
    gemm_tile<true>(aRdBase + p * 32768, bRdBase + p * 32768,
                    ldsA, ldsB, agA, agB, w, ub, acc);

    // C/D layout: col = lane&15, row = (lane>>4)*4 + reg
    const size_t crow0 = m0 + wgm * 128 + qq * 4;
    const size_t ccol0 = n0 + wgn * 64 + r;
    #pragma unroll
    for (int fm = 0; fm < 8; ++fm)
        #pragma unroll
        for (int fn = 0; fn < 4; ++fn)
            #pragma unroll
            for (int e = 0; e < 4; ++e)
                C[(crow0 + fm * 16 + e) * D_OUT + ccol0 + fn * 16] = acc[fm][fn][e];
}

extern "C" void kernel_launch(void* const* d_in, const int* in_sizes, int n_in,
                              void* d_out, int out_size, void* d_ws, size_t ws_size,
                              hipStream_t stream) {
    const float* x       = (const float*)d_in[0];
    const int*   qweight = (const int*)  d_in[1];
    const int*   qzeros  = (const int*)  d_in[2];
    const float* scales  = (const float*)d_in[3];
    const float* loraA   = (const float*)d_in[4];
    const float* loraB   = (const float*)d_in[5];
    float* out = (float*)d_out;

    // ws layout: W_t bf16 [D_OUT][D_IN] (32 MB) | x bf16 [M_TOT][D_IN] (64 MB)
    __hip_bfloat16* wt = (__hip_bfloat16*)d_ws;
    __hip_bfloat16* xb = (__hip_bfloat16*)((char*)d_ws + (size_t)D_OUT * D_IN * 2);

    static bool attr_set = false;
    if (!attr_set) {
        hipFuncSetAttribute(reinterpret_cast<const void*>(gemm_xw),
                            hipFuncAttributeMaxDynamicSharedMemorySize, 131072);
        attr_set = true;
    }

    build_wt<<<dim3(D_IN / 64, D_OUT / 64), 256, 0, stream>>>(
        qweight, qzeros, scales, loraA, loraB, wt);
    cvt_x<<<dim3((size_t)M_TOT * D_IN / (256 * 8)), 256, 0, stream>>>(x, xb);
    gemm_xw<<<dim3(NWG), 512, 131072, stream>>>(xb, wt, out);
}

// Round 2
// 522.785 us; speedup vs baseline: 1.2794x; 1.0102x over previous
//
#include <hip/hip_runtime.h>
#include <hip/hip_bf16.h>
#include <stdint.h>

#define D_IN    4096
#define D_OUT   4096
#define M_TOT   8192          // B*S = 4*2048
#define R_LORA  16
#define SCALING 2.0f          // lora_alpha / r

typedef __bf16 bf16x8 __attribute__((ext_vector_type(8)));
typedef float  f32x4  __attribute__((ext_vector_type(4)));
typedef short  s16x8  __attribute__((ext_vector_type(8)));

__device__ __forceinline__ void async_ld16(const void* g, void* l) {
    __builtin_amdgcn_global_load_lds(
        (const __attribute__((address_space(1))) void*)g,
        (__attribute__((address_space(3))) void*)l,
        16, 0, 0);
}

// raw barrier (no vmcnt drain) + compiler memory fence on both sides
#define BAR() do { asm volatile("" ::: "memory"); \
                   __builtin_amdgcn_s_barrier(); \
                   asm volatile("" ::: "memory"); } while (0)
#define WAIT_VM(n) asm volatile("s_waitcnt vmcnt(" #n ")" ::: "memory")

// ---------------------------------------------------------------------------
// Kernel 1 (fused prep): blocks [0,4096) build W_t; blocks [4096,20480) cvt x.
// One launch -> build's latency-bound blocks overlap cvt's BW-bound blocks.
// ---------------------------------------------------------------------------
#define NB_BUILD 4096
#define NB_CVT   16384

__global__ __launch_bounds__(256) void prep(
    const int*   __restrict__ qweight,   // [D_IN][D_OUT]
    const int*   __restrict__ qzeros,    // [D_IN/128][D_OUT]
    const float* __restrict__ scales,    // [D_IN/128][D_OUT]
    const float* __restrict__ loraA,     // [R][D_IN]
    const float* __restrict__ loraB,     // [D_OUT][R]
    const float* __restrict__ x,         // [M_TOT][D_IN] fp32
    __hip_bfloat16* __restrict__ wt,     // [D_OUT][D_IN]
    __hip_bfloat16* __restrict__ xb)     // [M_TOT][D_IN] bf16
{
    __shared__ float tile[64][65];       // +1 pad: conflict-free transposed read
    __shared__ float Abuf[16][64];       // loraA[r][i_off] (wave-uniform reads)

    const int b = blockIdx.x;
    const int t = threadIdx.x;

    if (b >= NB_BUILD) {
        // ---- cvt: x fp32 -> bf16, 8 elems/thread, 16B stores ----
        size_t idx = ((size_t)(b - NB_BUILD) * 256 + t) * 8;
        f32x4 a = *(const f32x4*)(x + idx);
        f32x4 c = *(const f32x4*)(x + idx + 4);
        union { __hip_bfloat16 h[8]; s16x8 v; } u;
        u.h[0] = __float2bfloat16(a[0]); u.h[1] = __float2bfloat16(a[1]);
        u.h[2] = __float2bfloat16(a[2]); u.h[3] = __float2bfloat16(a[3]);
        u.h[4] = __float2bfloat16(c[0]); u.h[5] = __float2bfloat16(c[1]);
        u.h[6] = __float2bfloat16(c[2]); u.h[7] = __float2bfloat16(c[3]);
        *(s16x8*)(xb + idx) = u.v;
        return;
    }

    // ---- build W_t[o][i] = (q[i,o]-z)*s + 2*sum_r A[r,i]*B[o,r] ----
    const int i0 = (b & 63) * 64;
    const int o0 = (b >> 6) * 64;

    for (int j = t; j < 16 * 64; j += 256) {
        int r = j >> 6, io = j & 63;
        Abuf[r][io] = loraA[r * D_IN + i0 + io];
    }
    const int oo = t & 63;
    const float* bp = loraB + (size_t)(o0 + oo) * R_LORA;   // regs, not LDS
    f32x4 bA = *(const f32x4*)(bp + 0);
    f32x4 bB = *(const f32x4*)(bp + 4);
    f32x4 bC = *(const f32x4*)(bp + 8);
    f32x4 bD = *(const f32x4*)(bp + 12);
    __syncthreads();

    const int g  = i0 >> 7;              // 64-aligned tile never crosses a group
    const int   zero = qzeros[g * D_OUT + o0 + oo];
    const float sc   = scales[g * D_OUT + o0 + oo];

    #pragma unroll                        // 16 iters: issue all q-loads up front
    for (int ii = (t >> 6); ii < 64; ii += 4) {
        int q = qweight[(size_t)(i0 + ii) * D_OUT + o0 + oo];
        float w = (float)(q - zero) * sc;
        float acc = 0.f;
        #pragma unroll
        for (int r = 0; r < 4; ++r)
            acc += Abuf[r][ii]      * bA[r] + Abuf[r + 4][ii]  * bB[r]
                 + Abuf[r + 8][ii]  * bC[r] + Abuf[r + 12][ii] * bD[r];
        tile[ii][oo] = w + SCALING * acc;
    }
    __syncthreads();

    const int i_off  = (t & 31) * 2;
    const int o_base = t >> 5;
    #pragma unroll
    for (int p = 0; p < 8; ++p) {
        int o = o_base + p * 8;
        __hip_bfloat162 v;
        v.x = __float2bfloat16(tile[i_off][o]);
        v.y = __float2bfloat16(tile[i_off + 1][o]);
        *(__hip_bfloat162*)&wt[(size_t)(o0 + o) * D_IN + i0 + i_off] = v;
    }
}

// ---------------------------------------------------------------------------
// Kernel 2: 256x256x64 GEMM, 3-phase/tile, barrier-BEFORE-MFMA only.
//
// LDS layout / staging / fragment-read order identical to round 1 (verified,
// 0 bank conflicts). Change: intra-tile barriers are scheduling-only (double
// buffered), so each phase is [ds_reads | stage issue | vmcnt | BAR | MFMA].
// No barrier after MFMA: a wave falls through into the next phase's ds_reads
// while other waves' MFMAs still execute -> LDS reads overlap matrix pipe.
// Guarantee chain for staged data: own WAIT_VM -> BAR -> reads that follow.
//   P1  : reads af0-3(F1A), bf01(F1B); stage F1A'; vmcnt(4) drains F2B
//   P2  : reads bf23(F2B);             stage F1B'; vmcnt(4) drains F3A
//   P34 : reads af4-7(F3A);  stage F2B',F3A';      vmcnt(4) drains F1A',F1B'
// Every drained quarter is >=2 phases old -> wait is free.
// ---------------------------------------------------------------------------
#define RDA(fm, ks) (*(const bf16x8*)(aRd + ((fm) * 2 + (ks)) * 1024))
#define RDB(fn, ks) (*(const bf16x8*)(bRd + ((fn) * 2 + (ks)) * 1024))

template<bool LAST>
__device__ __forceinline__ void gemm_tile(
    const char* __restrict__ aRd, const char* __restrict__ bRd,
    char* __restrict__ ldsAn, char* __restrict__ ldsBn,
    const __hip_bfloat16* __restrict__ agA,
    const __hip_bfloat16* __restrict__ agB,
    const int w, const int ub, f32x4 (&acc)[8][4])
{
    bf16x8 af[4][2], bf0[2][2], bf1[2][2];

    // ---- P1: reads af03+bf01, stage F1A', wait, BAR, MFMA (m0-3 x n0-1) ----
    #pragma unroll
    for (int fm = 0; fm < 4; ++fm) { af[fm][0] = RDA(fm, 0); af[fm][1] = RDA(fm, 1); }
    #pragma unroll
    for (int fn = 0; fn < 2; ++fn) { bf0[fn][0] = RDB(fn, 0); bf0[fn][1] = RDB(fn, 1); }
    if constexpr (!LAST) {
        async_ld16(agA,                      ldsAn + w * 1024);
        async_ld16(agA + (size_t)128 * D_IN, ldsAn + (16 + w) * 1024);
    }
    if constexpr (LAST) { WAIT_VM(2); } else { WAIT_VM(4); }
    BAR();
    __builtin_amdgcn_s_setprio(1);
    #pragma unroll
    for (int fm = 0; fm < 4; ++fm)
        #pragma unroll
        for (int fn = 0; fn < 2; ++fn)
            #pragma unroll
            for (int ks = 0; ks < 2; ++ks)
                acc[fm][fn] = __builtin_amdgcn_mfma_f32_16x16x32_bf16(
                    af[fm][ks], bf0[fn][ks], acc[fm][fn], 0, 0, 0);
    __builtin_amdgcn_s_setprio(0);

    // ---- P2: reads bf23, stage F1B', wait, BAR, MFMA (m0-3 x n2-3) ----
    #pragma unroll
    for (int fn = 0; fn < 2; ++fn) { bf1[fn][0] = RDB(fn + 2, 0); bf1[fn][1] = RDB(fn + 2, 1); }
    if constexpr (!LAST) {
        async_ld16(agB,                      ldsBn + ub * 1024);
        async_ld16(agB + (size_t)128 * D_IN, ldsBn + (ub + 16) * 1024);
    }
    if constexpr (LAST) { WAIT_VM(0); } else { WAIT_VM(4); }
    BAR();
    __builtin_amdgcn_s_setprio(1);
    #pragma unroll
    for (int fm = 0; fm < 4; ++fm)
        #pragma unroll
        for (int fn = 0; fn < 2; ++fn)
            #pragma unroll
            for (int ks = 0; ks < 2; ++ks)
                acc[fm][fn + 2] = __builtin_amdgcn_mfma_f32_16x16x32_bf16(
                    af[fm][ks], bf1[fn][ks], acc[fm][fn + 2], 0, 0, 0);
    __builtin_amdgcn_s_setprio(0);

    // ---- P34: reads af47, stage F2B'+F3A', wait, BAR, MFMA x32 ----
    #pragma unroll
    for (int fm = 0; fm < 4; ++fm) { af[fm][0] = RDA(fm + 4, 0); af[fm][1] = RDA(fm + 4, 1); }
    if constexpr (!LAST) {
        async_ld16(agB + (size_t)32 * D_IN,  ldsBn + (ub + 4) * 1024);
        async_ld16(agB + (size_t)160 * D_IN, ldsBn + (ub + 20) * 1024);
        async_ld16(agA + (size_t)64 * D_IN,  ldsAn + (8 + w) * 1024);
        async_ld16(agA + (size_t)192 * D_IN, ldsAn + (24 + w) * 1024);
        WAIT_VM(4);
    }
    BAR();
    __builtin_amdgcn_s_setprio(1);
    #pragma unroll
    for (int fm = 0; fm < 4; ++fm)
        #pragma unroll
        for (int fn = 0; fn < 2; ++fn)
            #pragma unroll
            for (int ks = 0; ks < 2; ++ks)
                acc[fm + 4][fn + 2] = __builtin_amdgcn_mfma_f32_16x16x32_bf16(
                    af[fm][ks], bf1[fn][ks], acc[fm + 4][fn + 2], 0, 0, 0);
    #pragma unroll
    for (int fm = 0; fm < 4; ++fm)
        #pragma unroll
        for (int fn = 0; fn < 2; ++fn)
            #pragma unroll
            for (int ks = 0; ks < 2; ++ks)
                acc[fm + 4][fn] = __builtin_amdgcn_mfma_f32_16x16x32_bf16(
                    af[fm][ks], bf0[fn][ks], acc[fm + 4][fn], 0, 0, 0);
    __builtin_amdgcn_s_setprio(0);
}

#define BK 64
#define NKT (D_IN / BK)        // 64
#define NWG ((M_TOT / 256) * (D_OUT / 256))   // 32*16 = 512

__global__ __launch_bounds__(512) void gemm_xw(
    const __hip_bfloat16* __restrict__ A,   // [M_TOT][D_IN] bf16
    const __hip_bfloat16* __restrict__ Bt,  // [D_OUT][D_IN] bf16
    float* __restrict__ C)                  // [M_TOT][D_OUT] fp32
{
    extern __shared__ __attribute__((aligned(16))) char lds[];
    char* ldsA = lds;            // [buf0 32K][buf1 32K]
    char* ldsB = lds + 65536;    // [buf0 32K][buf1 32K]

    const int t    = threadIdx.x;
    const int lane = t & 63;
    const int w    = t >> 6;       // 0..7
    const int wgm  = w >> 2;       // 0..1  (row half of C tile)
    const int wgn  = w & 3;        // 0..3  (col quarter)

    // XCD-aware bijective swizzle (NWG % 8 == 0)
    int wg = (int)blockIdx.x;
    wg = (wg & 7) * (NWG / 8) + (wg >> 3);
    const size_t m0 = (size_t)(wg >> 4) * 256;   // D_OUT/256 = 16 col-blocks
    const size_t n0 = (size_t)(wg & 15) * 256;

    const int r  = lane & 15;
    const int qq = lane >> 4;

    // per-thread global staging sources (chunk (r,qq) of this wave's subtiles)
    const size_t arow = m0 + (size_t)(((w >> 1) & 3) * 16 + r);
    const size_t brow = n0 + (size_t)((((w >> 2) & 1) * 4 + ((w >> 1) & 1)) * 16 + r);
    const int    col  = (w & 1) * 32 + qq * 8;
    const __hip_bfloat16* agA = A  + arow * D_IN + col;
    const __hip_bfloat16* agB = Bt + brow * D_IN + col;
    const int ub = (w & 3) + (w >> 2) * 8;       // B staging subtile base

    // per-thread LDS fragment-read bases (lane*16 linear within subtile)
    const char* aRdBase = ldsA + wgm * 16384 + lane * 16;
    const char* bRdBase = ldsB + (wgn >> 1) * 16384 + (wgn & 1) * 8192 + lane * 16;

    f32x4 acc[8][4] = {};

    // prologue: stage all 4 quarters of tile 0 into buf0 (order = wait order)
    async_ld16(agA,                      ldsA + w * 1024);
    async_ld16(agA + (size_t)128 * D_IN, ldsA + (16 + w) * 1024);
    async_ld16(agB,                      ldsB + ub * 1024);
    async_ld16(agB + (size_t)128 * D_IN, ldsB + (ub + 16) * 1024);
    async_ld16(agB + (size_t)32 * D_IN,  ldsB + (ub + 4) * 1024);
    async_ld16(agB + (size_t)160 * D_IN, ldsB + (ub + 20) * 1024);
    async_ld16(agA + (size_t)64 * D_IN,  ldsA + (8 + w) * 1024);
    async_ld16(agA + (size_t)192 * D_IN, ldsA + (24 + w) * 1024);
    WAIT_VM(4);   // F1A,F1B landed; F2B,F3A still in flight
    BAR();

    int p = 0;
    for (int kt = 0; kt < NKT - 1; ++kt) {
        const int kn = (kt + 1) * BK;
        gemm_tile<false>(aRdBase + p * 32768, bRdBase + p * 32768,
                         ldsA + (p ^ 1) * 32768, ldsB + (p ^ 1) * 32768,
                         agA + kn, agB + kn, w, ub, acc);
        p ^= 1;
    }
    gemm_tile<true>(aRdBase + p * 32768, bRdBase + p * 32768,
                    ldsA, ldsB, agA, agB, w, ub, acc);

    // C/D layout: col = lane&15, row = (lane>>4)*4 + reg
    const size_t crow0 = m0 + wgm * 128 + qq * 4;
    const size_t ccol0 = n0 + wgn * 64 + r;
    #pragma unroll
    for (int fm = 0; fm < 8; ++fm)
        #pragma unroll
        for (int fn = 0; fn < 4; ++fn)
            #pragma unroll
            for (int e = 0; e < 4; ++e)
                C[(crow0 + fm * 16 + e) * D_OUT + ccol0 + fn * 16] = acc[fm][fn][e];
}

extern "C" void kernel_launch(void* const* d_in, const int* in_sizes, int n_in,
                              void* d_out, int out_size, void* d_ws, size_t ws_size,
                              hipStream_t stream) {
    const float* x       = (const float*)d_in[0];
    const int*   qweight = (const int*)  d_in[1];
    const int*   qzeros  = (const int*)  d_in[2];
    const float* scales  = (const float*)d_in[3];
    const float* loraA   = (const float*)d_in[4];
    const float* loraB   = (const float*)d_in[5];
    float* out = (float*)d_out;

    // ws layout: W_t bf16 [D_OUT][D_IN] (32 MB) | x bf16 [M_TOT][D_IN] (64 MB)
    __hip_bfloat16* wt = (__hip_bfloat16*)d_ws;
    __hip_bfloat16* xb = (__hip_bfloat16*)((char*)d_ws + (size_t)D_OUT * D_IN * 2);

    static bool attr_set = false;
    if (!attr_set) {
        hipFuncSetAttribute(reinterpret_cast<const void*>(gemm_xw),
                            hipFuncAttributeMaxDynamicSharedMemorySize, 131072);
        attr_set = true;
    }

    prep<<<dim3(NB_BUILD + NB_CVT), 256, 0, stream>>>(
        qweight, qzeros, scales, loraA, loraB, x, wt, xb);
    gemm_xw<<<dim3(NWG), 512, 131072, stream>>>(xb, wt, out);
}